// Round 1
// baseline (8580.412 us; speedup 1.0000x reference)
//
#include <hip/hip_runtime.h>

// ---------------------------------------------------------------------------
// Sememe-LSTM, MI355X (gfx950).
// Phase 1: precompute_gemm  — fp32 vector SGEMM producing (transposed) streams:
//   iouT[1536][16384] = inputs@W_ioux^T + sememe_h@W_ious^T + b_ioux+b_ious+b_iouh
//   fxT [512][16384]  = inputs@W_fx^T + b_fx + b_fh
//   fscT[512][16384]  = sigmoid(inputs@W_fxs^T + sememe_h@W_fs^T + b_fxs+b_fs) * sememe_c
// Phase 2: lstm_rec — persistent grid (128 wg), per-wg 4 m-columns, recurrent
//   h@W term via 16x16x32 bf16 MFMA with fp32->(hi,lo) bf16 split (3 products),
//   weights resident in VGPRs as A-fragments, grid barrier per step.
// ---------------------------------------------------------------------------

#define T_STEPS 256
#define BATCH   64
#define MEM     512
#define INDIM   512
#define ROWS    (T_STEPS * BATCH)   // 16384

typedef __attribute__((ext_vector_type(8))) short bf16x8;
typedef __attribute__((ext_vector_type(4))) float f32x4;

__device__ __forceinline__ short f2bf(float x) {
  unsigned u = __builtin_bit_cast(unsigned, x);
  u = u + 0x7fffu + ((u >> 16) & 1u);   // RNE to bf16
  return (short)(u >> 16);
}
__device__ __forceinline__ float bf2f(short s) {
  unsigned u = ((unsigned)(unsigned short)s) << 16;
  return __builtin_bit_cast(float, u);
}

// ---------------------------------------------------------------------------
// Phase 1: fp32 SGEMM. Block = 128x128, BK=32, 256 threads, 8x8 micro-tile.
// Col-space: [0,1536) iou | [1536,2048) fx | [2048,2560) fs  -> 20 col tiles.
// Outputs stored TRANSPOSED ([col][row]) so phase 2 reads are coalesced.
// ---------------------------------------------------------------------------
#define BM 128
#define BN 128
#define BKK 32

__global__ __launch_bounds__(256) void precompute_gemm(
    const float* __restrict__ inputs,
    const float* __restrict__ sememe_c,
    const float* __restrict__ sememe_h,
    const float* __restrict__ W_ioux, const float* __restrict__ b_ioux,
    const float* __restrict__ b_iouh,
    const float* __restrict__ W_ious, const float* __restrict__ b_ious,
    const float* __restrict__ W_fx,   const float* __restrict__ b_fx,
    const float* __restrict__ W_fxs,  const float* __restrict__ b_fxs,
    const float* __restrict__ b_fh,
    const float* __restrict__ W_fs,   const float* __restrict__ b_fs,
    float* __restrict__ iouT, float* __restrict__ fxT, float* __restrict__ fscT)
{
  __shared__ float As[BKK][BM + 4];
  __shared__ float Ws[BKK][BN + 4];

  const int bx  = blockIdx.x;       // 0..2559
  const int ct  = bx % 20;
  const int rt  = bx / 20;
  const int tid = threadIdx.x;
  const int tx  = tid & 15;         // col micro index
  const int ty  = tid >> 4;         // row micro index
  const int r0  = rt * BM;

  const int region = (ct < 12) ? 0 : (ct < 16 ? 1 : 2);
  const int cbase  = (region == 0) ? ct * 128 : (region == 1 ? (ct - 12) * 128 : (ct - 16) * 128);

  const float* A0; const float* W0; const float* A1 = nullptr; const float* W1 = nullptr;
  int npass;
  if (region == 0)      { A0 = inputs; W0 = W_ioux + (size_t)cbase * INDIM; A1 = sememe_h; W1 = W_ious + (size_t)cbase * INDIM; npass = 2; }
  else if (region == 1) { A0 = inputs; W0 = W_fx   + (size_t)cbase * INDIM; npass = 1; }
  else                  { A0 = inputs; W0 = W_fxs  + (size_t)cbase * INDIM; A1 = sememe_h; W1 = W_fs + (size_t)cbase * INDIM; npass = 2; }

  float acc[8][8] = {};

  for (int pass = 0; pass < npass; ++pass) {
    const float* Ap = ((pass == 0) ? A0 : A1) + (size_t)r0 * INDIM;
    const float* Wp = (pass == 0) ? W0 : W1;
    for (int kt = 0; kt < INDIM / BKK; ++kt) {
      __syncthreads();   // protect previous tile reads before overwrite
#pragma unroll
      for (int l = 0; l < 4; ++l) {
        int e  = tid + l * 256;     // 0..1023 float4 slots
        int kq = e & 7;             // 8 quads = 32 k
        int rr = e >> 3;            // 0..127
        float4 va = *(const float4*)(Ap + (size_t)rr * INDIM + kt * BKK + kq * 4);
        As[kq * 4 + 0][rr] = va.x; As[kq * 4 + 1][rr] = va.y;
        As[kq * 4 + 2][rr] = va.z; As[kq * 4 + 3][rr] = va.w;
        float4 vw = *(const float4*)(Wp + (size_t)rr * INDIM + kt * BKK + kq * 4);
        Ws[kq * 4 + 0][rr] = vw.x; Ws[kq * 4 + 1][rr] = vw.y;
        Ws[kq * 4 + 2][rr] = vw.z; Ws[kq * 4 + 3][rr] = vw.w;
      }
      __syncthreads();
#pragma unroll
      for (int kk = 0; kk < BKK; ++kk) {
        float a[8], b[8];
        *(float4*)&a[0] = *(const float4*)&As[kk][ty * 8];
        *(float4*)&a[4] = *(const float4*)&As[kk][ty * 8 + 4];
        *(float4*)&b[0] = *(const float4*)&Ws[kk][tx * 8];
        *(float4*)&b[4] = *(const float4*)&Ws[kk][tx * 8 + 4];
#pragma unroll
        for (int i = 0; i < 8; ++i)
#pragma unroll
          for (int j = 0; j < 8; ++j)
            acc[i][j] += a[i] * b[j];
      }
    }
  }

  const int i0 = ty * 8, j0 = tx * 8;
  if (region == 0) {
#pragma unroll
    for (int j = 0; j < 8; ++j) {
      int c = cbase + j0 + j;
      float bias = b_ioux[c] + b_ious[c] + b_iouh[c];
      float* dst = iouT + (size_t)c * ROWS + r0 + i0;
      float o[8];
#pragma unroll
      for (int i = 0; i < 8; ++i) o[i] = acc[i][j] + bias;
      *(float4*)(dst)     = *(float4*)&o[0];
      *(float4*)(dst + 4) = *(float4*)&o[4];
    }
  } else if (region == 1) {
#pragma unroll
    for (int j = 0; j < 8; ++j) {
      int c = cbase + j0 + j;
      float bias = b_fx[c] + b_fh[c];   // fold b_fh here
      float* dst = fxT + (size_t)c * ROWS + r0 + i0;
      float o[8];
#pragma unroll
      for (int i = 0; i < 8; ++i) o[i] = acc[i][j] + bias;
      *(float4*)(dst)     = *(float4*)&o[0];
      *(float4*)(dst + 4) = *(float4*)&o[4];
    }
  } else {
#pragma unroll
    for (int j = 0; j < 8; ++j) {
      int c = cbase + j0 + j;
      float bias = b_fxs[c] + b_fs[c];
      float* dst = fscT + (size_t)c * ROWS + r0 + i0;
      float o[8];
#pragma unroll
      for (int i = 0; i < 8; ++i) {
        float z = acc[i][j] + bias;
        float s = 1.f / (1.f + expf(-z));
        o[i] = s * sememe_c[(size_t)(r0 + i0 + i) * MEM + c];
      }
      *(float4*)(dst)     = *(float4*)&o[0];
      *(float4*)(dst + 4) = *(float4*)&o[4];
    }
  }
}

// ---------------------------------------------------------------------------
// Phase 2: recurrence. 128 wg x 256 thr. wg owns m-block of 4 (16 gate rows:
// r = 0..3 -> i(m0..m0+3), 4..7 -> o, 8..11 -> u, 12..15 -> f).
// A-fragments (weights, hi/lo bf16) persist in VGPRs. Wave w handles b-quarter
// [16w,16w+16). Per step: 16 k-tiles x 3 split-MFMAs; D layout col=lane&15,
// rows (lane>>4)*4+i -> LDS -> per-(b,m) combine thread; c-state in VGPR.
// ---------------------------------------------------------------------------
__device__ __forceinline__ float sigmoidf_(float x) { return 1.f / (1.f + expf(-x)); }

__global__ __launch_bounds__(256, 1) void lstm_rec(
    const float* __restrict__ iouT,
    const float* __restrict__ fxT,
    const float* __restrict__ fscT,
    const float* __restrict__ W_iouh,
    const float* __restrict__ W_fh,
    unsigned short* __restrict__ hbuf,   // [2 bufs][hi|lo][64][512] bf16 bits
    int* __restrict__ bar,               // [0]=count [1]=generation
    float* __restrict__ out)             // [16384][512]
{
  const int wg   = blockIdx.x;     // 0..127
  const int m0   = wg * 4;
  const int tid  = threadIdx.x;
  const int lane = tid & 63;
  const int wv   = tid >> 6;       // wave -> b-quarter

  // ---- persistent weight fragments ----
  const int arow = lane & 15;      // A row = gate row
  const int kgrp = lane >> 4;      // k-subgroup (8 elems)
  const int q = arow >> 2, jj = arow & 3;
  const float* wrow = (q < 3) ? (W_iouh + (size_t)(q * MEM + m0 + jj) * MEM)
                              : (W_fh   + (size_t)(m0 + jj) * MEM);
  bf16x8 Ahi[16], Alo[16];
#pragma unroll
  for (int kt = 0; kt < 16; ++kt) {
    const float* wp = wrow + kt * 32 + kgrp * 8;
    bf16x8 hi, lo;
#pragma unroll
    for (int e = 0; e < 8; ++e) {
      float w = wp[e];
      short h16 = f2bf(w);
      hi[e] = h16;
      lo[e] = f2bf(w - bf2f(h16));
    }
    Ahi[kt] = hi; Alo[kt] = lo;
  }

  __shared__ float preLDS[64 * 18];   // [b][16 rows], stride 18 kills bank conflicts

  // ---- combine-thread mapping: thread -> (b, m0+cj) ----
  const int cb = tid & 63;
  const int cj = tid >> 6;
  const float* p_i = iouT + (size_t)(m0 + cj) * ROWS;
  const float* p_o = iouT + (size_t)(512 + m0 + cj) * ROWS;
  const float* p_u = iouT + (size_t)(1024 + m0 + cj) * ROWS;
  const float* p_f = fxT  + (size_t)(m0 + cj) * ROWS;
  const float* p_s = fscT + (size_t)(m0 + cj) * ROWS;
  float* p_out = out + (size_t)cb * MEM + m0 + cj;

  const int bb   = wv * 16 + (lane & 15);   // B-frag col -> batch row
  const int koff = kgrp * 8;

  float c_reg = 0.f;
  const int nwg = (int)gridDim.x;

  for (int t = 0; t < T_STEPS; ++t) {
    const int rb = t & 1, wb = rb ^ 1;
    const int row = t * BATCH + cb;
    // issue pre-activation stream loads early; they overlap the MFMA phase
    float ip = p_i[row], op = p_o[row], up = p_u[row], fp = p_f[row], sv = p_s[row];

    const unsigned short* hh = hbuf + (size_t)rb * 2 * BATCH * MEM;
    const unsigned short* hl = hh + BATCH * MEM;
    const unsigned short* hhp = hh + (size_t)bb * MEM + koff;
    const unsigned short* hlp = hl + (size_t)bb * MEM + koff;

    f32x4 acc = {0.f, 0.f, 0.f, 0.f};
#pragma unroll
    for (int kt = 0; kt < 16; ++kt) {
      bf16x8 bhi = *(const bf16x8*)(hhp + kt * 32);
      bf16x8 blo = *(const bf16x8*)(hlp + kt * 32);
      acc = __builtin_amdgcn_mfma_f32_16x16x32_bf16(Ahi[kt], bhi, acc, 0, 0, 0);
      acc = __builtin_amdgcn_mfma_f32_16x16x32_bf16(Ahi[kt], blo, acc, 0, 0, 0);
      acc = __builtin_amdgcn_mfma_f32_16x16x32_bf16(Alo[kt], bhi, acc, 0, 0, 0);
    }
    // D -> LDS: lane holds col b'=lane&15 (b = bb), rows kgrp*4+i
#pragma unroll
    for (int i = 0; i < 4; ++i) preLDS[bb * 18 + kgrp * 4 + i] = acc[i];
    __syncthreads();

    float pi = ip + preLDS[cb * 18 + 0  + cj];
    float po = op + preLDS[cb * 18 + 4  + cj];
    float pu = up + preLDS[cb * 18 + 8  + cj];
    float pf = fp + preLDS[cb * 18 + 12 + cj];
    float ig = sigmoidf_(pi);
    float og = sigmoidf_(po);
    float ug = tanhf(pu);
    float fg = sigmoidf_(pf);
    float cc = ig * ug + fg * c_reg + sv;
    float hv = og * tanhf(cc);
    c_reg = cc;
    p_out[(size_t)t * BATCH * MEM] = hv;

    // split h -> next buffer
    short h16 = f2bf(hv);
    short l16 = f2bf(hv - bf2f(h16));
    unsigned short* wh = hbuf + (size_t)wb * 2 * BATCH * MEM;
    wh[cb * MEM + m0 + cj]              = (unsigned short)h16;
    wh[BATCH * MEM + cb * MEM + m0 + cj] = (unsigned short)l16;

    if (t == T_STEPS - 1) break;   // no readers after the last step

    // ---- grid barrier (sense via generation counter) ----
    __syncthreads();               // drain this wg's stores (waitcnt before s_barrier)
    if (tid == 0) {
      __threadfence();             // agent-scope release of h stores
      int g = __hip_atomic_load(&bar[1], __ATOMIC_RELAXED, __HIP_MEMORY_SCOPE_AGENT);
      int a = __hip_atomic_fetch_add(&bar[0], 1, __ATOMIC_ACQ_REL, __HIP_MEMORY_SCOPE_AGENT);
      if (a == nwg - 1) {
        __hip_atomic_store(&bar[0], 0, __ATOMIC_RELAXED, __HIP_MEMORY_SCOPE_AGENT);
        __hip_atomic_fetch_add(&bar[1], 1, __ATOMIC_RELEASE, __HIP_MEMORY_SCOPE_AGENT);
      } else {
        while (__hip_atomic_load(&bar[1], __ATOMIC_ACQUIRE, __HIP_MEMORY_SCOPE_AGENT) == g) {
          __builtin_amdgcn_s_sleep(2);
        }
      }
    }
    __syncthreads();               // also protects preLDS reuse next step
  }
}

// ---------------------------------------------------------------------------
extern "C" void kernel_launch(void* const* d_in, const int* in_sizes, int n_in,
                              void* d_out, int out_size, void* d_ws, size_t ws_size,
                              hipStream_t stream) {
  const float* inputs   = (const float*)d_in[0];
  const float* sememe_c = (const float*)d_in[1];
  const float* sememe_h = (const float*)d_in[2];
  const float* W_ioux   = (const float*)d_in[3];
  const float* b_ioux   = (const float*)d_in[4];
  const float* W_iouh   = (const float*)d_in[5];
  const float* b_iouh   = (const float*)d_in[6];
  const float* W_ious   = (const float*)d_in[7];
  const float* b_ious   = (const float*)d_in[8];
  const float* W_fx     = (const float*)d_in[9];
  const float* b_fx     = (const float*)d_in[10];
  const float* W_fxs    = (const float*)d_in[11];
  const float* b_fxs    = (const float*)d_in[12];
  const float* W_fh     = (const float*)d_in[13];
  const float* b_fh     = (const float*)d_in[14];
  const float* W_fs     = (const float*)d_in[15];
  const float* b_fs     = (const float*)d_in[16];

  float* iouT = (float*)d_ws;                          // [1536][16384]
  float* fxT  = iouT + (size_t)1536 * ROWS;            // [512][16384]
  float* fscT = fxT  + (size_t)512 * ROWS;             // [512][16384]
  unsigned short* hbuf = (unsigned short*)(fscT + (size_t)512 * ROWS); // 2*2*64*512
  int* bar = (int*)(hbuf + (size_t)2 * 2 * BATCH * MEM);

  // zero h buffer 0 (h_0 = 0) + barrier state (ws is poisoned 0xAA each call)
  hipMemsetAsync(hbuf, 0, (size_t)2 * 2 * BATCH * MEM * sizeof(unsigned short) + 128, stream);

  precompute_gemm<<<dim3(2560), dim3(256), 0, stream>>>(
      inputs, sememe_c, sememe_h,
      W_ioux, b_ioux, b_iouh, W_ious, b_ious,
      W_fx, b_fx, W_fxs, b_fxs, b_fh, W_fs, b_fs,
      iouT, fxT, fscT);

  lstm_rec<<<dim3(128), dim3(256), 0, stream>>>(
      iouT, fxT, fscT, W_iouh, W_fh, hbuf, bar, (float*)d_out);
}

// Round 2
// 2802.512 us; speedup vs baseline: 3.0617x; 3.0617x over previous
//
#include <hip/hip_runtime.h>

// ---------------------------------------------------------------------------
// Sememe-LSTM, MI355X (gfx950).
// Phase 1: precompute_gemm  — fp32 vector SGEMM producing (transposed) streams.
// Phase 2: lstm_rec — 4 independent batch-groups (16 rows) x 32 wgs (16 m each).
//   Weights in VGPRs (hi/lo bf16 split), h exchanged through the MALL with
//   sc0/sc1 write-through stores + relaxed monotonic-count group barriers.
//   NO __threadfence (agent fences emit buffer_wbl2/inv = 497MB/call writeback
//   flood observed in round 1).
// ---------------------------------------------------------------------------

#define T_STEPS 256
#define BATCH   64
#define MEM     512
#define INDIM   512
#define ROWS    (T_STEPS * BATCH)   // 16384

typedef __attribute__((ext_vector_type(8))) short bf16x8;
typedef __attribute__((ext_vector_type(4))) float f32x4;
typedef __attribute__((ext_vector_type(4))) unsigned int u32x4;

__device__ __forceinline__ short f2bf(float x) {
  unsigned u = __builtin_bit_cast(unsigned, x);
  u = u + 0x7fffu + ((u >> 16) & 1u);   // RNE to bf16
  return (short)(u >> 16);
}
__device__ __forceinline__ float bf2f(short s) {
  unsigned u = ((unsigned)(unsigned short)s) << 16;
  return __builtin_bit_cast(float, u);
}

// Device-coherent (MALL) 16B load / 2B store: sc0 sc1 bypass L1+L2 so no
// cache-maintenance fences are needed for cross-XCD producer/consumer.
__device__ __forceinline__ u32x4 load16_sc(const void* p) {
  u32x4 r;
  asm volatile("global_load_dwordx4 %0, %1, off sc0 sc1" : "=v"(r) : "v"(p) : "memory");
  return r;
}
__device__ __forceinline__ void store2_sc(void* p, unsigned v) {
  asm volatile("global_store_short %0, %1, off sc0 sc1" :: "v"(p), "v"(v) : "memory");
}

// ---------------------------------------------------------------------------
// Phase 1: fp32 SGEMM (unchanged from round 1; 1.3 ms, second priority).
// ---------------------------------------------------------------------------
#define BM 128
#define BN 128
#define BKK 32

__global__ __launch_bounds__(256) void precompute_gemm(
    const float* __restrict__ inputs,
    const float* __restrict__ sememe_c,
    const float* __restrict__ sememe_h,
    const float* __restrict__ W_ioux, const float* __restrict__ b_ioux,
    const float* __restrict__ b_iouh,
    const float* __restrict__ W_ious, const float* __restrict__ b_ious,
    const float* __restrict__ W_fx,   const float* __restrict__ b_fx,
    const float* __restrict__ W_fxs,  const float* __restrict__ b_fxs,
    const float* __restrict__ b_fh,
    const float* __restrict__ W_fs,   const float* __restrict__ b_fs,
    float* __restrict__ iouT, float* __restrict__ fxT, float* __restrict__ fscT)
{
  __shared__ float As[BKK][BM + 4];
  __shared__ float Ws[BKK][BN + 4];

  const int bx  = blockIdx.x;       // 0..2559
  const int ct  = bx % 20;
  const int rt  = bx / 20;
  const int tid = threadIdx.x;
  const int tx  = tid & 15;
  const int ty  = tid >> 4;
  const int r0  = rt * BM;

  const int region = (ct < 12) ? 0 : (ct < 16 ? 1 : 2);
  const int cbase  = (region == 0) ? ct * 128 : (region == 1 ? (ct - 12) * 128 : (ct - 16) * 128);

  const float* A0; const float* W0; const float* A1 = nullptr; const float* W1 = nullptr;
  int npass;
  if (region == 0)      { A0 = inputs; W0 = W_ioux + (size_t)cbase * INDIM; A1 = sememe_h; W1 = W_ious + (size_t)cbase * INDIM; npass = 2; }
  else if (region == 1) { A0 = inputs; W0 = W_fx   + (size_t)cbase * INDIM; npass = 1; }
  else                  { A0 = inputs; W0 = W_fxs  + (size_t)cbase * INDIM; A1 = sememe_h; W1 = W_fs + (size_t)cbase * INDIM; npass = 2; }

  float acc[8][8] = {};

  for (int pass = 0; pass < npass; ++pass) {
    const float* Ap = ((pass == 0) ? A0 : A1) + (size_t)r0 * INDIM;
    const float* Wp = (pass == 0) ? W0 : W1;
    for (int kt = 0; kt < INDIM / BKK; ++kt) {
      __syncthreads();
#pragma unroll
      for (int l = 0; l < 4; ++l) {
        int e  = tid + l * 256;
        int kq = e & 7;
        int rr = e >> 3;
        float4 va = *(const float4*)(Ap + (size_t)rr * INDIM + kt * BKK + kq * 4);
        As[kq * 4 + 0][rr] = va.x; As[kq * 4 + 1][rr] = va.y;
        As[kq * 4 + 2][rr] = va.z; As[kq * 4 + 3][rr] = va.w;
        float4 vw = *(const float4*)(Wp + (size_t)rr * INDIM + kt * BKK + kq * 4);
        Ws[kq * 4 + 0][rr] = vw.x; Ws[kq * 4 + 1][rr] = vw.y;
        Ws[kq * 4 + 2][rr] = vw.z; Ws[kq * 4 + 3][rr] = vw.w;
      }
      __syncthreads();
#pragma unroll
      for (int kk = 0; kk < BKK; ++kk) {
        float a[8], b[8];
        *(float4*)&a[0] = *(const float4*)&As[kk][ty * 8];
        *(float4*)&a[4] = *(const float4*)&As[kk][ty * 8 + 4];
        *(float4*)&b[0] = *(const float4*)&Ws[kk][tx * 8];
        *(float4*)&b[4] = *(const float4*)&Ws[kk][tx * 8 + 4];
#pragma unroll
        for (int i = 0; i < 8; ++i)
#pragma unroll
          for (int j = 0; j < 8; ++j)
            acc[i][j] += a[i] * b[j];
      }
    }
  }

  const int i0 = ty * 8, j0 = tx * 8;
  if (region == 0) {
#pragma unroll
    for (int j = 0; j < 8; ++j) {
      int c = cbase + j0 + j;
      float bias = b_ioux[c] + b_ious[c] + b_iouh[c];
      float* dst = iouT + (size_t)c * ROWS + r0 + i0;
      float o[8];
#pragma unroll
      for (int i = 0; i < 8; ++i) o[i] = acc[i][j] + bias;
      *(float4*)(dst)     = *(float4*)&o[0];
      *(float4*)(dst + 4) = *(float4*)&o[4];
    }
  } else if (region == 1) {
#pragma unroll
    for (int j = 0; j < 8; ++j) {
      int c = cbase + j0 + j;
      float bias = b_fx[c] + b_fh[c];
      float* dst = fxT + (size_t)c * ROWS + r0 + i0;
      float o[8];
#pragma unroll
      for (int i = 0; i < 8; ++i) o[i] = acc[i][j] + bias;
      *(float4*)(dst)     = *(float4*)&o[0];
      *(float4*)(dst + 4) = *(float4*)&o[4];
    }
  } else {
#pragma unroll
    for (int j = 0; j < 8; ++j) {
      int c = cbase + j0 + j;
      float bias = b_fxs[c] + b_fs[c];
      float* dst = fscT + (size_t)c * ROWS + r0 + i0;
      float o[8];
#pragma unroll
      for (int i = 0; i < 8; ++i) {
        float z = acc[i][j] + bias;
        float s = 1.f / (1.f + expf(-z));
        o[i] = s * sememe_c[(size_t)(r0 + i0 + i) * MEM + c];
      }
      *(float4*)(dst)     = *(float4*)&o[0];
      *(float4*)(dst + 4) = *(float4*)&o[4];
    }
  }
}

// ---------------------------------------------------------------------------
// Phase 2: recurrence.
// Grid 128 = 4 batch-groups (16 rows) x 32 m-wgs (16 m-cols = 64 gate rows).
// Wave wv = gate wv (i,o,u,f); holds 16 weight rows as hi/lo bf16 A-frags.
// Per step: stage group h (32KB) -> LDS; 16 kt x 3 split-MFMAs (4 acc chains);
// D -> preLDS -> combine threads; h hi/lo short-stores (sc0 sc1) -> MALL;
// relaxed monotonic-count barrier per group (32 participants).
// hbuf layout: [group 0..3][buf 0..1][hi|lo][16 b][512 m] ushort.
// bar: int[group*32], monotonic count, target 32*(t+1).
// ---------------------------------------------------------------------------
__device__ __forceinline__ float sigmoidf_(float x) { return 1.f / (1.f + expf(-x)); }

__global__ __launch_bounds__(256, 1) void lstm_rec(
    const float* __restrict__ iouT,
    const float* __restrict__ fxT,
    const float* __restrict__ fscT,
    const float* __restrict__ W_iouh,
    const float* __restrict__ W_fh,
    unsigned short* __restrict__ hbuf,
    int* __restrict__ bar,
    float* __restrict__ out)             // [16384][512]
{
  const int wg   = blockIdx.x;     // 0..127
  const int bg   = wg >> 5;        // batch group 0..3
  const int gm   = wg & 31;        // m-block 0..31
  const int m0   = gm * 16;
  const int B0   = bg * 16;
  const int tid  = threadIdx.x;
  const int lane = tid & 63;
  const int wv   = tid >> 6;       // wave = gate (0=i,1=o,2=u,3=f)

  // ---- persistent weight fragments: wave wv, rows m0+arow of its gate ----
  const int arow = lane & 15;
  const int kgrp = lane >> 4;
  const float* wrow = (wv < 3) ? (W_iouh + (size_t)(wv * MEM + m0 + arow) * MEM)
                               : (W_fh   + (size_t)(m0 + arow) * MEM);
  bf16x8 Ahi[16], Alo[16];
#pragma unroll
  for (int kt = 0; kt < 16; ++kt) {
    const float* wp = wrow + kt * 32 + kgrp * 8;
    bf16x8 hi, lo;
#pragma unroll
    for (int e = 0; e < 8; ++e) {
      float w = wp[e];
      short h16 = f2bf(w);
      hi[e] = h16;
      lo[e] = f2bf(w - bf2f(h16));
    }
    Ahi[kt] = hi; Alo[kt] = lo;
  }

  __shared__ __align__(16) unsigned short BhiL[16][520];  // +8 pad: conflict-free b128 reads
  __shared__ __align__(16) unsigned short BloL[16][520];
  __shared__ float preLDS[16 * 68];                       // [b][4 gates x 16 m], stride 68

  unsigned short* hg = hbuf + (size_t)bg * 2 * 2 * 16 * MEM;  // group base
  int* barp = bar + bg * 32;                                   // group line (128B apart)

  // combine mapping: thread -> (b8 = tid&15, mj = tid>>4)
  const int b8 = tid & 15;
  const int mj = tid >> 4;
  const int m  = m0 + mj;
  const float* p_i = iouT + (size_t)m * ROWS;
  const float* p_o = iouT + (size_t)(MEM + m) * ROWS;
  const float* p_u = iouT + (size_t)(2 * MEM + m) * ROWS;
  const float* p_f = fxT  + (size_t)m * ROWS;
  const float* p_s = fscT + (size_t)m * ROWS;

  // stage mapping: thread -> (srow = tid>>4, sseg = tid&15)
  const int srow = tid >> 4;
  const int sseg = tid & 15;

  const int bb = lane & 15;        // MFMA B-col = batch row within group

  float c_reg = 0.f;

  for (int t = 0; t < T_STEPS; ++t) {
    const int rb  = t & 1;
    const int row = t * BATCH + B0 + b8;
    // pre-activation streams (plain cached loads; L2 stays warm — no invalidates)
    float ip = p_i[row], op = p_o[row], up = p_u[row], fp = p_f[row], sv = p_s[row];

    // ---- stage group h (hi+lo, 32KB) -> LDS, one waitcnt ----
    const char* hbase = (const char*)(hg + (size_t)rb * 2 * 16 * MEM);
    const char* ghi = hbase + srow * 1024;
    const char* glo = hbase + 16 * 1024 + srow * 1024;
    u32x4 v0 = load16_sc(ghi + 0 * 256 + sseg * 16);
    u32x4 v1 = load16_sc(ghi + 1 * 256 + sseg * 16);
    u32x4 v2 = load16_sc(ghi + 2 * 256 + sseg * 16);
    u32x4 v3 = load16_sc(ghi + 3 * 256 + sseg * 16);
    u32x4 w0 = load16_sc(glo + 0 * 256 + sseg * 16);
    u32x4 w1 = load16_sc(glo + 1 * 256 + sseg * 16);
    u32x4 w2 = load16_sc(glo + 2 * 256 + sseg * 16);
    u32x4 w3 = load16_sc(glo + 3 * 256 + sseg * 16);
    asm volatile("s_waitcnt vmcnt(0)" ::: "memory");
    __builtin_amdgcn_sched_barrier(0);
    *(u32x4*)&BhiL[srow][0 * 128 + sseg * 8] = v0;
    *(u32x4*)&BhiL[srow][1 * 128 + sseg * 8] = v1;
    *(u32x4*)&BhiL[srow][2 * 128 + sseg * 8] = v2;
    *(u32x4*)&BhiL[srow][3 * 128 + sseg * 8] = v3;
    *(u32x4*)&BloL[srow][0 * 128 + sseg * 8] = w0;
    *(u32x4*)&BloL[srow][1 * 128 + sseg * 8] = w1;
    *(u32x4*)&BloL[srow][2 * 128 + sseg * 8] = w2;
    *(u32x4*)&BloL[srow][3 * 128 + sseg * 8] = w3;
    __syncthreads();

    // ---- MFMA: 16 kt x 3 split products, 4 interleaved acc chains ----
    f32x4 acc[4] = {{0.f,0.f,0.f,0.f},{0.f,0.f,0.f,0.f},{0.f,0.f,0.f,0.f},{0.f,0.f,0.f,0.f}};
#pragma unroll
    for (int kt = 0; kt < 16; ++kt) {
      bf16x8 bhiF = *(const bf16x8*)&BhiL[bb][kt * 32 + kgrp * 8];
      bf16x8 bloF = *(const bf16x8*)&BloL[bb][kt * 32 + kgrp * 8];
      acc[(3 * kt + 0) & 3] = __builtin_amdgcn_mfma_f32_16x16x32_bf16(Ahi[kt], bhiF, acc[(3 * kt + 0) & 3], 0, 0, 0);
      acc[(3 * kt + 1) & 3] = __builtin_amdgcn_mfma_f32_16x16x32_bf16(Ahi[kt], bloF, acc[(3 * kt + 1) & 3], 0, 0, 0);
      acc[(3 * kt + 2) & 3] = __builtin_amdgcn_mfma_f32_16x16x32_bf16(Alo[kt], bhiF, acc[(3 * kt + 2) & 3], 0, 0, 0);
    }
    f32x4 accs = (acc[0] + acc[1]) + (acc[2] + acc[3]);
    // D layout: col = lane&15 (=bb), rows kgrp*4+i (= m-offset within gate)
#pragma unroll
    for (int i = 0; i < 4; ++i) preLDS[bb * 68 + wv * 16 + kgrp * 4 + i] = accs[i];
    __syncthreads();

    // ---- combine: gates + state update ----
    float pi = ip + preLDS[b8 * 68 + 0  + mj];
    float po = op + preLDS[b8 * 68 + 16 + mj];
    float pu = up + preLDS[b8 * 68 + 32 + mj];
    float pf = fp + preLDS[b8 * 68 + 48 + mj];
    float ig = sigmoidf_(pi);
    float og = sigmoidf_(po);
    float ug = tanhf(pu);
    float fg = sigmoidf_(pf);
    float cc = ig * ug + fg * c_reg + sv;
    float hv = og * tanhf(cc);
    c_reg = cc;
    out[(size_t)(t * BATCH + B0 + b8) * MEM + m] = hv;

    if (t == T_STEPS - 1) break;

    // ---- publish h (hi/lo split) to MALL ----
    short h16 = f2bf(hv);
    short l16 = f2bf(hv - bf2f(h16));
    unsigned short* wbase = hg + (size_t)(rb ^ 1) * 2 * 16 * MEM;
    store2_sc(wbase + b8 * MEM + m,            (unsigned)(unsigned short)h16);
    store2_sc(wbase + 16 * MEM + b8 * MEM + m, (unsigned)(unsigned short)l16);
    asm volatile("s_waitcnt vmcnt(0)" ::: "memory");   // acks at coherence point
    __syncthreads();                                   // all 256 threads' stores ack'd

    // ---- group barrier: relaxed monotonic count (no fences, no wbl2/inv) ----
    if (tid == 0) {
      __hip_atomic_fetch_add(&barp[0], 1, __ATOMIC_RELAXED, __HIP_MEMORY_SCOPE_AGENT);
      const int target = 32 * (t + 1);
      while (__hip_atomic_load(&barp[0], __ATOMIC_RELAXED, __HIP_MEMORY_SCOPE_AGENT) < target)
        __builtin_amdgcn_s_sleep(1);
    }
    __syncthreads();
  }
}

// ---------------------------------------------------------------------------
extern "C" void kernel_launch(void* const* d_in, const int* in_sizes, int n_in,
                              void* d_out, int out_size, void* d_ws, size_t ws_size,
                              hipStream_t stream) {
  const float* inputs   = (const float*)d_in[0];
  const float* sememe_c = (const float*)d_in[1];
  const float* sememe_h = (const float*)d_in[2];
  const float* W_ioux   = (const float*)d_in[3];
  const float* b_ioux   = (const float*)d_in[4];
  const float* W_iouh   = (const float*)d_in[5];
  const float* b_iouh   = (const float*)d_in[6];
  const float* W_ious   = (const float*)d_in[7];
  const float* b_ious   = (const float*)d_in[8];
  const float* W_fx     = (const float*)d_in[9];
  const float* b_fx     = (const float*)d_in[10];
  const float* W_fxs    = (const float*)d_in[11];
  const float* b_fxs    = (const float*)d_in[12];
  const float* W_fh     = (const float*)d_in[13];
  const float* b_fh     = (const float*)d_in[14];
  const float* W_fs     = (const float*)d_in[15];
  const float* b_fs     = (const float*)d_in[16];

  float* iouT = (float*)d_ws;                          // [1536][16384]
  float* fxT  = iouT + (size_t)1536 * ROWS;            // [512][16384]
  float* fscT = fxT  + (size_t)512 * ROWS;             // [512][16384]
  unsigned short* hbuf = (unsigned short*)(fscT + (size_t)512 * ROWS); // 4 grp x 2 buf x 2 planes x 16x512
  int* bar = (int*)(hbuf + (size_t)4 * 2 * 2 * 16 * MEM);

  // zero h buffers (h_0 = 0) + barrier counters (ws is poisoned 0xAA each call)
  size_t hbytes = (size_t)4 * 2 * 2 * 16 * MEM * sizeof(unsigned short) + 4 * 32 * sizeof(int);
  hipMemsetAsync(hbuf, 0, hbytes, stream);

  precompute_gemm<<<dim3(2560), dim3(256), 0, stream>>>(
      inputs, sememe_c, sememe_h,
      W_ioux, b_ioux, b_iouh, W_ious, b_ious,
      W_fx, b_fx, W_fxs, b_fxs, b_fh, W_fs, b_fs,
      iouT, fxT, fscT);

  lstm_rec<<<dim3(128), dim3(256), 0, stream>>>(
      iouT, fxT, fscT, W_iouh, W_fh, hbuf, bar, (float*)d_out);
}

// Round 3
// 1485.321 us; speedup vs baseline: 5.7768x; 1.8868x over previous
//
#include <hip/hip_runtime.h>

// ---------------------------------------------------------------------------
// Sememe-LSTM, MI355X (gfx950).
// pack_act/pack_w: fp32 -> (hi,lo) bf16 split, pre-swizzled into LDS-shaped
//   tiles (128B rows, 16B slot ^= (row&7)) for conflict-free MFMA staging.
// gemm_mfma: 128x128 tile, 4 waves (2x2), 16x16x32 bf16 MFMA, 3-product
//   split => fp32-grade accuracy at ~bf16/3 rate. global_load_lds staging,
//   2-phase double buffer. Writes transposed streams + fused bias/sigmoid.
// lstm_rec: 4 groups x 32 wgs; weights in VGPRs; h exchanged as packed
//   (hi<<16|lo) dwords via MALL (sc0 sc1), coalesced via LDS transpose;
//   flag-line barrier (no atomics).
// ---------------------------------------------------------------------------

#define T_STEPS 256
#define BATCH   64
#define MEM     512
#define ROWS    16384

typedef __attribute__((ext_vector_type(8))) short bf16x8;
typedef __attribute__((ext_vector_type(4))) short short4v;
typedef __attribute__((ext_vector_type(4))) float f32x4;
typedef __attribute__((ext_vector_type(4))) unsigned int u32x4;

__device__ __forceinline__ short f2bf(float x) {
  unsigned u = __builtin_bit_cast(unsigned, x);
  u = u + 0x7fffu + ((u >> 16) & 1u);   // RNE to bf16
  return (short)(u >> 16);
}
__device__ __forceinline__ float bf2f(short s) {
  unsigned u = ((unsigned)(unsigned short)s) << 16;
  return __builtin_bit_cast(float, u);
}
__device__ __forceinline__ float sigmoidf_(float x) { return 1.f / (1.f + expf(-x)); }

// MALL-coherent (sc0 sc1) ops — cross-XCD safe without cache-maintenance fences.
__device__ __forceinline__ u32x4 load16_sc(const void* p) {
  u32x4 r;
  asm volatile("global_load_dwordx4 %0, %1, off sc0 sc1" : "=v"(r) : "v"(p) : "memory");
  return r;
}
__device__ __forceinline__ void store4_sc(void* p, unsigned v) {
  asm volatile("global_store_dword %0, %1, off sc0 sc1" :: "v"(p), "v"(v) : "memory");
}
__device__ __forceinline__ unsigned poll4_sc(const void* p) {
  unsigned r;
  asm volatile("global_load_dword %0, %1, off sc0 sc1\ns_waitcnt vmcnt(0)"
               : "=v"(r) : "v"(p) : "memory");
  return r;
}

// ---------------------------------------------------------------------------
// pack_act: inputs/sememe_h [16384][512] f32 -> Apack[(rt*32+kt)*128+r][128B]
// kt 0..15 = inputs k-chunks, 16..31 = sememe_h. Row r: 8 slots of 16B,
// physical slot = logical ^ (r&7); logical 0..3 = hi k-octets, 4..7 = lo.
// ---------------------------------------------------------------------------
__global__ __launch_bounds__(256) void pack_act(
    const float* __restrict__ inputs, const float* __restrict__ sememe_h,
    char* __restrict__ Apack)
{
  int gid = blockIdx.x * 256 + threadIdx.x;    // 2^21 threads
  int sel = gid >> 20;
  int rem = gid & 1048575;
  int R = rem >> 6, kg = rem & 63;
  const float* src = (sel ? sememe_h : inputs) + (size_t)R * 512 + kg * 8;
  float4 a = *(const float4*)src;
  float4 b = *(const float4*)(src + 4);
  float v[8] = {a.x, a.y, a.z, a.w, b.x, b.y, b.z, b.w};
  bf16x8 hi8, lo8;
#pragma unroll
  for (int e = 0; e < 8; ++e) {
    short h = f2bf(v[e]);
    hi8[e] = h;
    lo8[e] = f2bf(v[e] - bf2f(h));
  }
  int rt = R >> 7, r = R & 127, kt = sel * 16 + (kg >> 2), ls = kg & 3;
  char* rowp = Apack + ((size_t)((rt * 32 + kt) * 128 + r)) * 128;
  *(bf16x8*)(rowp + ((ls ^ (r & 7)) << 4))       = hi8;
  *(bf16x8*)(rowp + (((4 + ls) ^ (r & 7)) << 4)) = lo8;
}

// ---------------------------------------------------------------------------
// pack_w: weights -> Wpack[(ct*32+kt)*128+cc][128B], same swizzle keyed by cc.
// ct 0..11: W_ioux(kt<16)/W_ious(kt>=16); 12..15: W_fx(kt<16); 16..19:
// W_fxs/W_fs.
// ---------------------------------------------------------------------------
__global__ __launch_bounds__(256) void pack_w(
    const float* __restrict__ W_ioux, const float* __restrict__ W_ious,
    const float* __restrict__ W_fx,   const float* __restrict__ W_fxs,
    const float* __restrict__ W_fs,   char* __restrict__ Wpack)
{
  int gid = blockIdx.x * 256 + threadIdx.x;    // 20*32*128*4 = 327680
  if (gid >= 20 * 32 * 128 * 4) return;
  int ct = gid >> 14;
  int rem = gid & 16383;
  int ktv = rem >> 9;
  int rem2 = rem & 511;
  int cc = rem2 >> 2, kg = rem2 & 3;
  int region = (ct < 12) ? 0 : (ct < 16 ? 1 : 2);
  if (region == 1 && ktv >= 16) return;        // unused slots stay poisoned
  const float* srcrow;
  int k0;
  if (region == 0) {
    int c = ct * 128 + cc;
    if (ktv < 16) { srcrow = W_ioux + (size_t)c * 512; k0 = ktv * 32 + kg * 8; }
    else          { srcrow = W_ious + (size_t)c * 512; k0 = (ktv - 16) * 32 + kg * 8; }
  } else if (region == 1) {
    int c = (ct - 12) * 128 + cc;
    srcrow = W_fx + (size_t)c * 512; k0 = ktv * 32 + kg * 8;
  } else {
    int c = (ct - 16) * 128 + cc;
    if (ktv < 16) { srcrow = W_fxs + (size_t)c * 512; k0 = ktv * 32 + kg * 8; }
    else          { srcrow = W_fs  + (size_t)c * 512; k0 = (ktv - 16) * 32 + kg * 8; }
  }
  float4 a = *(const float4*)(srcrow + k0);
  float4 b = *(const float4*)(srcrow + k0 + 4);
  float v[8] = {a.x, a.y, a.z, a.w, b.x, b.y, b.z, b.w};
  bf16x8 hi8, lo8;
#pragma unroll
  for (int e = 0; e < 8; ++e) {
    short h = f2bf(v[e]);
    hi8[e] = h;
    lo8[e] = f2bf(v[e] - bf2f(h));
  }
  char* rowp = Wpack + ((size_t)((ct * 32 + ktv) * 128 + cc)) * 128;
  *(bf16x8*)(rowp + ((kg ^ (cc & 7)) << 4))       = hi8;
  *(bf16x8*)(rowp + (((4 + kg) ^ (cc & 7)) << 4)) = lo8;
}

// ---------------------------------------------------------------------------
// gemm_mfma: block 128 rows x 128 cols, 256 thr (4 waves 2x2, wave tile 64x64
// = 4x4 frags of 16x16). A-operand = W rows (M=cols), B-operand = act rows
// (N=rows) so D col(lane&15)=row r (coalesced store), D row(reg)=col c.
// ---------------------------------------------------------------------------
#define GLL(gsrc, ldst) __builtin_amdgcn_global_load_lds( \
    (const __attribute__((address_space(1))) unsigned*)(gsrc), \
    (__attribute__((address_space(3))) unsigned*)(ldst), 16, 0, 0)

__global__ __launch_bounds__(256, 2) void gemm_mfma(
    const char* __restrict__ Apack, const char* __restrict__ Wpack,
    const float* __restrict__ sememe_c,
    const float* __restrict__ b_ioux, const float* __restrict__ b_iouh,
    const float* __restrict__ b_ious, const float* __restrict__ b_fx,
    const float* __restrict__ b_fh,  const float* __restrict__ b_fxs,
    const float* __restrict__ b_fs,
    float* __restrict__ iouT, float* __restrict__ fxT, float* __restrict__ fscT)
{
  __shared__ char ldsb[65536];     // 2 bufs x (W 16K + A 16K)
  __shared__ float bsum[128];

  const int bx = blockIdx.x;
  const int swz = (bx & 7) * 320 + (bx >> 3);   // XCD-chunk swizzle (2560%8==0)
  const int rt = swz / 20, ct = swz % 20;
  const int tid = threadIdx.x, lane = tid & 63, wv = tid >> 6;
  const int wm = wv >> 1, wn = wv & 1;
  const int l15 = lane & 15, kgrp = lane >> 4;

  const int region = (ct < 12) ? 0 : (ct < 16 ? 1 : 2);
  const int cb0 = (region == 0) ? ct * 128 : (region == 1 ? (ct - 12) * 128 : (ct - 16) * 128);
  const int nkt = (region == 1) ? 16 : 32;

  if (tid < 128) {
    int c = cb0 + tid;
    bsum[tid] = (region == 0) ? b_ioux[c] + b_ious[c] + b_iouh[c]
              : (region == 1) ? b_fx[c] + b_fh[c]
                              : b_fxs[c] + b_fs[c];
  }

  const char* Ablk0 = Apack + (size_t)rt * 32 * 16384;
  const char* Wblk0 = Wpack + (size_t)ct * 32 * 16384;

  // loop-invariant per-lane frag byte offsets (within a 16KB tile)
  int aoffH[4], aoffL[4], boffH[4], boffL[4];
#pragma unroll
  for (int f = 0; f < 4; ++f) {
    int c_loc = wm * 64 + f * 16 + l15;
    aoffH[f] = c_loc * 128 + ((kgrp ^ (c_loc & 7)) << 4);
    aoffL[f] = c_loc * 128 + (((4 + kgrp) ^ (c_loc & 7)) << 4);
    int r_loc = wn * 64 + f * 16 + l15;
    boffH[f] = r_loc * 128 + ((kgrp ^ (r_loc & 7)) << 4);
    boffL[f] = r_loc * 128 + (((4 + kgrp) ^ (r_loc & 7)) << 4);
  }

#define STAGE(ktv, buf) do { \
    const char* As_ = Ablk0 + (size_t)(ktv) * 16384; \
    const char* Ws_ = Wblk0 + (size_t)(ktv) * 16384; \
    char* Ld_ = ldsb + (buf) * 32768; \
    _Pragma("unroll") \
    for (int i_ = 0; i_ < 4; ++i_) { \
      int off_ = (wv * 4 + i_) * 1024; \
      GLL(Ws_ + off_ + lane * 16, Ld_ + off_); \
      GLL(As_ + off_ + lane * 16, Ld_ + 16384 + off_); \
    } } while (0)

  f32x4 acc[4][4];
#pragma unroll
  for (int a = 0; a < 4; ++a)
#pragma unroll
    for (int b = 0; b < 4; ++b) acc[a][b] = (f32x4){0.f, 0.f, 0.f, 0.f};

  STAGE(0, 0);
  asm volatile("s_waitcnt vmcnt(0)" ::: "memory");
  __syncthreads();

  for (int kt = 0; kt < nkt; ++kt) {
    const int cur = kt & 1;
    if (kt + 1 < nkt) STAGE(kt + 1, cur ^ 1);
    const char* Wt = ldsb + cur * 32768;
    const char* At = Wt + 16384;
    bf16x8 AH[4], AL[4], BH[4], BL[4];
#pragma unroll
    for (int f = 0; f < 4; ++f) {
      AH[f] = *(const bf16x8*)(Wt + aoffH[f]);
      AL[f] = *(const bf16x8*)(Wt + aoffL[f]);
      BH[f] = *(const bf16x8*)(At + boffH[f]);
      BL[f] = *(const bf16x8*)(At + boffL[f]);
    }
#pragma unroll
    for (int fm = 0; fm < 4; ++fm)
#pragma unroll
      for (int fn = 0; fn < 4; ++fn) {
        acc[fm][fn] = __builtin_amdgcn_mfma_f32_16x16x32_bf16(AH[fm], BH[fn], acc[fm][fn], 0, 0, 0);
        acc[fm][fn] = __builtin_amdgcn_mfma_f32_16x16x32_bf16(AH[fm], BL[fn], acc[fm][fn], 0, 0, 0);
        acc[fm][fn] = __builtin_amdgcn_mfma_f32_16x16x32_bf16(AL[fm], BH[fn], acc[fm][fn], 0, 0, 0);
      }
    asm volatile("s_waitcnt vmcnt(0)" ::: "memory");
    __syncthreads();
  }

  // epilogue: bias (+ region2 sigmoid*sememe_c), store transposed [col][row]
  const int r0 = rt * 128;
  float* stream = (region == 0) ? iouT : (region == 1) ? fxT : fscT;
#pragma unroll
  for (int fm = 0; fm < 4; ++fm)
#pragma unroll
    for (int fn = 0; fn < 4; ++fn) {
      int rr = r0 + wn * 64 + fn * 16 + l15;
#pragma unroll
      for (int i = 0; i < 4; ++i) {
        int c_loc = wm * 64 + fm * 16 + kgrp * 4 + i;
        float val = acc[fm][fn][i] + bsum[c_loc];
        if (region == 2)
          val = sigmoidf_(val) * sememe_c[(size_t)rr * MEM + cb0 + c_loc];
        stream[(size_t)(cb0 + c_loc) * ROWS + rr] = val;
      }
    }
}

// ---------------------------------------------------------------------------
// lstm_rec: 4 groups(16 b) x 32 wgs(16 m). h exchanged as packed dwords
// (hi<<16|lo) in hplane[group][buf][16 b][512 m]; coalesced publish via LDS
// transpose; flag-line barrier (store t+1, poll 32 flags, no atomics).
// ---------------------------------------------------------------------------
__global__ __launch_bounds__(256, 1) void lstm_rec(
    const float* __restrict__ iouT,
    const float* __restrict__ fxT,
    const float* __restrict__ fscT,
    const float* __restrict__ W_iouh,
    const float* __restrict__ W_fh,
    unsigned* __restrict__ hplane,
    int* __restrict__ flags,
    float* __restrict__ out)             // [16384][512]
{
  const int wg = blockIdx.x, bg = wg >> 5, gm = wg & 31;
  const int m0 = gm * 16, B0 = bg * 16;
  const int tid = threadIdx.x, lane = tid & 63, wv = tid >> 6;

  // ---- persistent weight fragments: wave = gate, rows m0+arow ----
  const int arow = lane & 15, kgrp = lane >> 4;
  const float* wrow = (wv < 3) ? (W_iouh + (size_t)(wv * MEM + m0 + arow) * MEM)
                               : (W_fh   + (size_t)(m0 + arow) * MEM);
  bf16x8 Ahi[16], Alo[16];
#pragma unroll
  for (int kt = 0; kt < 16; ++kt) {
    const float* wp = wrow + kt * 32 + kgrp * 8;
    bf16x8 hi, lo;
#pragma unroll
    for (int e = 0; e < 8; ++e) {
      float w = wp[e];
      short h16 = f2bf(w);
      hi[e] = h16;
      lo[e] = f2bf(w - bf2f(h16));
    }
    Ahi[kt] = hi; Alo[kt] = lo;
  }

  __shared__ __align__(16) unsigned short BhiL[16][520];
  __shared__ __align__(16) unsigned short BloL[16][520];
  __shared__ float preLDS[16 * 68];
  __shared__ unsigned hT[16 * 17];

  unsigned* hg = hplane + (size_t)bg * 2 * 8192;   // group base (dwords)
  int* flagp = flags + bg * 32;                    // group flag line (128B)

  const int b8 = tid & 15, mj = tid >> 4;
  const int m = m0 + mj;
  const float* p_i = iouT + (size_t)m * ROWS;
  const float* p_o = iouT + (size_t)(MEM + m) * ROWS;
  const float* p_u = iouT + (size_t)(2 * MEM + m) * ROWS;
  const float* p_f = fxT  + (size_t)m * ROWS;
  const float* p_s = fscT + (size_t)m * ROWS;

  const int bb = lane & 15;
  float c_reg = 0.f;

  for (int t = 0; t < T_STEPS; ++t) {
    const int rb = t & 1;
    const int row = t * BATCH + B0 + b8;
    float ip = p_i[row], op = p_o[row], up = p_u[row], fp = p_f[row], sv = p_s[row];

    // ---- stage packed h plane (32KB) -> LDS hi/lo tiles ----
    const unsigned* hPr = hg + (size_t)rb * 8192;
    u32x4 V[8];
#pragma unroll
    for (int i = 0; i < 8; ++i) V[i] = load16_sc(hPr + i * 1024 + tid * 4);
    asm volatile("s_waitcnt vmcnt(0)" ::: "memory");
    __builtin_amdgcn_sched_barrier(0);
#pragma unroll
    for (int i = 0; i < 8; ++i) {
      int d = i * 1024 + tid * 4;
      int b = d >> 9, mm = d & 511;
      u32x4 v = V[i];
      short4v hi4 = {(short)(v[0] >> 16), (short)(v[1] >> 16),
                     (short)(v[2] >> 16), (short)(v[3] >> 16)};
      short4v lo4 = {(short)(v[0] & 0xffff), (short)(v[1] & 0xffff),
                     (short)(v[2] & 0xffff), (short)(v[3] & 0xffff)};
      *(short4v*)&BhiL[b][mm] = hi4;
      *(short4v*)&BloL[b][mm] = lo4;
    }
    __syncthreads();

    // ---- MFMA: 16 kt x 3 split products, 4 interleaved acc chains ----
    f32x4 acc[4] = {{0.f,0.f,0.f,0.f},{0.f,0.f,0.f,0.f},{0.f,0.f,0.f,0.f},{0.f,0.f,0.f,0.f}};
#pragma unroll
    for (int kt = 0; kt < 16; ++kt) {
      bf16x8 bhiF = *(const bf16x8*)&BhiL[bb][kt * 32 + kgrp * 8];
      bf16x8 bloF = *(const bf16x8*)&BloL[bb][kt * 32 + kgrp * 8];
      acc[(3 * kt + 0) & 3] = __builtin_amdgcn_mfma_f32_16x16x32_bf16(Ahi[kt], bhiF, acc[(3 * kt + 0) & 3], 0, 0, 0);
      acc[(3 * kt + 1) & 3] = __builtin_amdgcn_mfma_f32_16x16x32_bf16(Ahi[kt], bloF, acc[(3 * kt + 1) & 3], 0, 0, 0);
      acc[(3 * kt + 2) & 3] = __builtin_amdgcn_mfma_f32_16x16x32_bf16(Alo[kt], bhiF, acc[(3 * kt + 2) & 3], 0, 0, 0);
    }
    f32x4 accs = (acc[0] + acc[1]) + (acc[2] + acc[3]);
#pragma unroll
    for (int i = 0; i < 4; ++i) preLDS[bb * 68 + wv * 16 + kgrp * 4 + i] = accs[i];
    __syncthreads();

    // ---- combine ----
    float pi = ip + preLDS[b8 * 68 + 0  + mj];
    float po = op + preLDS[b8 * 68 + 16 + mj];
    float pu = up + preLDS[b8 * 68 + 32 + mj];
    float pf = fp + preLDS[b8 * 68 + 48 + mj];
    float ig = sigmoidf_(pi);
    float og = sigmoidf_(po);
    float ug = tanhf(pu);
    float fg = sigmoidf_(pf);
    float cc = ig * ug + fg * c_reg + sv;
    float hv = og * tanhf(cc);
    c_reg = cc;
    out[(size_t)(t * BATCH + B0 + b8) * MEM + m] = hv;

    if (t == T_STEPS - 1) break;

    // ---- publish h: pack, LDS transpose, coalesced sc stores ----
    short h16 = f2bf(hv);
    short l16 = f2bf(hv - bf2f(h16));
    unsigned hu = ((unsigned)(unsigned short)h16 << 16) | (unsigned short)l16;
    hT[b8 * 17 + mj] = hu;
    __syncthreads();
    {
      int bs = tid >> 4, ms = tid & 15;
      unsigned v = hT[bs * 17 + ms];
      store4_sc(hg + (size_t)(rb ^ 1) * 8192 + bs * 512 + m0 + ms, v);
    }
    asm volatile("s_waitcnt vmcnt(0)" ::: "memory");   // own stores at MALL
    __syncthreads();                                   // whole wg's stores acked

    // ---- flag-line barrier: store t+1, one wave polls all 32 flags ----
    if (tid == 0) store4_sc(flagp + gm, (unsigned)(t + 1));
    if (wv == 0) {
      const int need = t + 1;
      int ok = (lane >= 32) ? 1 : 0;
      while (!__all(ok)) {
        if (!ok) ok = ((int)poll4_sc(flagp + (lane & 31)) >= need) ? 1 : 0;
      }
    }
    __syncthreads();
  }
}

// ---------------------------------------------------------------------------
extern "C" void kernel_launch(void* const* d_in, const int* in_sizes, int n_in,
                              void* d_out, int out_size, void* d_ws, size_t ws_size,
                              hipStream_t stream) {
  const float* inputs   = (const float*)d_in[0];
  const float* sememe_c = (const float*)d_in[1];
  const float* sememe_h = (const float*)d_in[2];
  const float* W_ioux   = (const float*)d_in[3];
  const float* b_ioux   = (const float*)d_in[4];
  const float* W_iouh   = (const float*)d_in[5];
  const float* b_iouh   = (const float*)d_in[6];
  const float* W_ious   = (const float*)d_in[7];
  const float* b_ious   = (const float*)d_in[8];
  const float* W_fx     = (const float*)d_in[9];
  const float* b_fx     = (const float*)d_in[10];
  const float* W_fxs    = (const float*)d_in[11];
  const float* b_fxs    = (const float*)d_in[12];
  const float* W_fh     = (const float*)d_in[13];
  const float* b_fh     = (const float*)d_in[14];
  const float* W_fs     = (const float*)d_in[15];
  const float* b_fs     = (const float*)d_in[16];

  float* iouT = (float*)d_ws;                             // [1536][16384] f32
  float* fxT  = iouT + (size_t)1536 * ROWS;               // [512][16384]
  float* fscT = fxT  + (size_t)512 * ROWS;                // [512][16384]
  char*  Apack = (char*)(fscT + (size_t)512 * ROWS);      // 67,108,864 B
  char*  Wpack = Apack + (size_t)128 * 32 * 128 * 128;    // 10,485,760 B
  unsigned* hplane = (unsigned*)(Wpack + (size_t)20 * 32 * 128 * 128);  // 262,144 B
  int* flags = (int*)(hplane + (size_t)4 * 2 * 8192);     // 512 B

  // zero h planes (h_0 = 0) + flags (ws is poisoned 0xAA each call)
  hipMemsetAsync(hplane, 0, (size_t)4 * 2 * 8192 * 4 + 512, stream);

  pack_act<<<dim3(8192), dim3(256), 0, stream>>>(inputs, sememe_h, Apack);
  pack_w<<<dim3(1280), dim3(256), 0, stream>>>(W_ioux, W_ious, W_fx, W_fxs, W_fs, Wpack);

  gemm_mfma<<<dim3(2560), dim3(256), 0, stream>>>(
      Apack, Wpack, sememe_c,
      b_ioux, b_iouh, b_ious, b_fx, b_fh, b_fxs, b_fs,
      iouT, fxT, fscT);

  lstm_rec<<<dim3(128), dim3(256), 0, stream>>>(
      iouT, fxT, fscT, W_iouh, W_fh, hplane, flags, (float*)d_out);
}